// Round 9
// baseline (471.497 us; speedup 1.0000x reference)
//
#include <hip/hip_runtime.h>
#include <math.h>

// Contextual loss, N=1, C=256, H=W=96 -> S=9216.
// loss = log(S) - log( sum_j exp( -vcol_j ) )
//   vcol_j = min_i [ a_i * d_ij + ln S'_i ]
//   S'_i   = sum_j exp( -a_i * d_ij )
//   a_i    = 2 / (m_i + 1e-5),  m_i = min_j d_ij,  d = clip((1-cos)/2, 0)
// cos = Iv^T Tv; Iv,Tv bf16, stored transposed [S][C] (K-contiguous, NT GEMM).
// R9: register diet for occupancy. A is NOT kept full-K in registers
// (that was 128 VGPRs -> +64 AGPR acc -> 2 waves/SIMD cap, the r3-r8
// plateau). Instead each kc slice stages A+B together (32 KB LDS), and
// only the current slice's fa (16 VGPRs) is live -> ~110 regs total ->
// 4 waves/SIMD. No pipelining (r4/r6/r7 all regressed).

typedef short v8s __attribute__((ext_vector_type(8)));
typedef float v4f __attribute__((ext_vector_type(4)));

static constexpr int Sn = 9216;
static constexpr int Cn = 256;

// ws float offsets
static constexpr size_t OFF_MEAN = 0;                      // 256 floats
static constexpr size_t OFF_MROW = 256;                    // Sn uint bits (row min d)
static constexpr size_t OFF_WROW = 256 + 9216;             // Sn floats (S'_i)
static constexpr size_t OFF_VCOL = 256 + 2 * 9216;         // Sn uint bits (col min v)
static constexpr size_t OFF_SUM  = 256 + 3 * 9216;         // 1 float
static constexpr size_t OFF_IV   = 32768;                  // Sn*Cn bf16
static constexpr size_t OFF_TV   = 32768 + (size_t)Sn * Cn / 2;

__device__ __forceinline__ unsigned bf16rne(float x) {
    unsigned u = __float_as_uint(x);
    return (u + 0x7FFFu + ((u >> 16) & 1u)) >> 16;
}

__device__ __forceinline__ void gload_lds16(const void* g, void* l) {
    __builtin_amdgcn_global_load_lds(
        (const __attribute__((address_space(1))) unsigned*)g,
        (__attribute__((address_space(3))) unsigned*)l, 16, 0, 0);
}

// ---------------- init ----------------
__global__ void k_init(float* ws) {
    int t = blockIdx.x * 256 + threadIdx.x;
    if (t < Sn) {
        ((unsigned*)(ws + OFF_MROW))[t] = 0x7F800000u;  // +inf
        ws[OFF_WROW + t] = 0.0f;
        ((unsigned*)(ws + OFF_VCOL))[t] = 0x7F800000u;  // +inf
    }
    if (t == 0) ws[OFF_SUM] = 0.0f;
}

// ---------------- per-channel mean of T ----------------
__global__ void k_mean(const float* __restrict__ T, float* ws) {
    __shared__ float red[256];
    int c = blockIdx.x;
    float s = 0.f;
    for (int i = threadIdx.x; i < Sn; i += 256) s += T[(size_t)c * Sn + i];
    red[threadIdx.x] = s;
    __syncthreads();
    for (int off = 128; off > 0; off >>= 1) {
        if (threadIdx.x < off) red[threadIdx.x] += red[threadIdx.x + off];
        __syncthreads();
    }
    if (threadIdx.x == 0) ws[OFF_MEAN + c] = red[0] * (1.0f / Sn);
}

// ------- center + L2 normalize along C, emit bf16 transposed [S][C] -------
__global__ __launch_bounds__(256) void k_norm(const float* __restrict__ I,
                                              const float* __restrict__ T,
                                              float* ws) {
    __shared__ float mc[256];
    __shared__ float redI[4][64], redT[4][64];
    __shared__ float riS[64], rtS[64];
    const int tid = threadIdx.x, sl = tid & 63, cq = tid >> 6;
    const int s = blockIdx.x * 64 + sl;
    mc[tid] = ws[OFF_MEAN + tid];
    __syncthreads();
    float si = 0.f, st = 0.f;
    for (int c = cq * 64; c < cq * 64 + 64; ++c) {
        float xi = I[(size_t)c * Sn + s] - mc[c];
        float xt = T[(size_t)c * Sn + s] - mc[c];
        si += xi * xi;
        st += xt * xt;
    }
    redI[cq][sl] = si;
    redT[cq][sl] = st;
    __syncthreads();
    if (tid < 64) {
        float a = redI[0][tid] + redI[1][tid] + redI[2][tid] + redI[3][tid];
        float b = redT[0][tid] + redT[1][tid] + redT[2][tid] + redT[3][tid];
        riS[tid] = 1.0f / fmaxf(sqrtf(a), 1e-12f);
        rtS[tid] = 1.0f / fmaxf(sqrtf(b), 1e-12f);
    }
    __syncthreads();
    const float ri = riS[sl], rt = rtS[sl];
    unsigned short* Iv = (unsigned short*)(ws + OFF_IV);
    unsigned short* Tv = (unsigned short*)(ws + OFF_TV);
    uint4* Ivq = (uint4*)(Iv + (size_t)s * Cn);
    uint4* Tvq = (uint4*)(Tv + (size_t)s * Cn);
    for (int c8 = cq * 8; c8 < cq * 8 + 8; ++c8) {
        unsigned iw[4], tw[4];
#pragma unroll
        for (int h = 0; h < 4; ++h) {
            int c0 = c8 * 8 + 2 * h, c1 = c0 + 1;
            float i0 = (I[(size_t)c0 * Sn + s] - mc[c0]) * ri;
            float i1 = (I[(size_t)c1 * Sn + s] - mc[c1]) * ri;
            float t0 = (T[(size_t)c0 * Sn + s] - mc[c0]) * rt;
            float t1 = (T[(size_t)c1 * Sn + s] - mc[c1]) * rt;
            iw[h] = bf16rne(i0) | (bf16rne(i1) << 16);
            tw[h] = bf16rne(t0) | (bf16rne(t1) << 16);
        }
        Ivq[c8] = make_uint4(iw[0], iw[1], iw[2], iw[3]);
        Tvq[c8] = make_uint4(tw[0], tw[1], tw[2], tw[3]);
    }
}

// Stage the kc-th K-slice of BOTH A and B tiles (16 KB each) into one
// 32 KB LDS buffer.  8-chunk XOR swizzle (p = c ^ (row&7)) applied on the
// global gather side; LDS dest = uniform base + lane*16.
__device__ __forceinline__ void stage_ab(const char* Ab, const char* Bb,
                                         char* lds, int kc, int tid) {
    const int lane = tid & 63, wave = tid >> 6;
    const int p = lane & 7;
#pragma unroll
    for (int w = 0; w < 4; ++w) {
        int gi = wave * 4 + w;
        int row = gi * 8 + (lane >> 3);
        int c = p ^ (row & 7);
        size_t goff = (size_t)row * 512 + kc * 128 + c * 16;
        gload_lds16(Ab + goff, lds + gi * 1024);
        gload_lds16(Bb + goff, lds + 16384 + gi * 1024);
    }
}

// One 128x128 tile, K=256, staging A+B per kc slice. Only the current
// slice's fa lives in registers (4 v8s). acc must be pre-zeroed.
__device__ __forceinline__ void tile_mma(const char* Ab, const char* Bb,
                                         char* lds, int tid, v4f acc[4][4]) {
    const int lane = tid & 63, wave = tid >> 6;
    const int wm = wave >> 1, wn = wave & 1, quad = (lane >> 4) & 3, l15 = lane & 15;
    for (int kc = 0; kc < 4; ++kc) {
        __syncthreads();
        stage_ab(Ab, Bb, lds, kc, tid);
        __syncthreads();
#pragma unroll
        for (int ks = 0; ks < 2; ++ks) {
            int cc = ks * 4 + quad;
            v8s fa[4];
#pragma unroll
            for (int mt = 0; mt < 4; ++mt) {
                int row = wm * 64 + mt * 16 + l15;
                fa[mt] = *(const v8s*)(lds + row * 128 + (cc ^ (row & 7)) * 16);
            }
#pragma unroll
            for (int nt = 0; nt < 4; ++nt) {
                int row = wn * 64 + nt * 16 + l15;
                v8s fb = *(const v8s*)(lds + 16384 + row * 128 + (cc ^ (row & 7)) * 16);
#pragma unroll
                for (int mt = 0; mt < 4; ++mt)
                    acc[mt][nt] = __builtin_amdgcn_mfma_f32_16x16x32_bf16(
                        fa[mt], fb, acc[mt][nt], 0, 0, 0);
            }
        }
    }
}

// ---------------- pass 1: m_i = min_j d_ij ----------------
__global__ __launch_bounds__(256, 4) void k_rowmin(float* ws) {
    __shared__ __align__(16) char lds[32768];
    const char* Ivb = (const char*)(ws + OFF_IV);
    const char* Tvb = (const char*)(ws + OFF_TV);
    const int tid = threadIdx.x, lane = tid & 63, wave = tid >> 6;
    const int wm = wave >> 1, quad = (lane >> 4) & 3, l15 = lane & 15;
    const int i0 = blockIdx.x * 128;
    const char* Ab = Ivb + (size_t)i0 * 512;
    float mv[4][4];
#pragma unroll
    for (int mt = 0; mt < 4; ++mt)
#pragma unroll
        for (int r = 0; r < 4; ++r) mv[mt][r] = INFINITY;
    for (int t = 0; t < 4; ++t) {
        int j0 = (blockIdx.y * 4 + t) * 128;
        v4f acc[4][4];
#pragma unroll
        for (int mt = 0; mt < 4; ++mt)
#pragma unroll
            for (int nt = 0; nt < 4; ++nt)
#pragma unroll
                for (int r = 0; r < 4; ++r) acc[mt][nt][r] = 0.f;
        tile_mma(Ab, Tvb + (size_t)j0 * 512, lds, tid, acc);
#pragma unroll
        for (int mt = 0; mt < 4; ++mt)
#pragma unroll
            for (int nt = 0; nt < 4; ++nt)
#pragma unroll
                for (int r = 0; r < 4; ++r) {
                    float d = fmaxf(0.5f - 0.5f * acc[mt][nt][r], 0.0f);
                    mv[mt][r] = fminf(mv[mt][r], d);
                }
    }
#pragma unroll
    for (int mt = 0; mt < 4; ++mt)
#pragma unroll
        for (int r = 0; r < 4; ++r) {
            float m = mv[mt][r];
            for (int off = 1; off < 16; off <<= 1)
                m = fminf(m, __shfl_xor(m, off, 64));
            if (l15 == 0)
                atomicMin((unsigned*)(ws + OFF_MROW) + i0 + wm * 64 + mt * 16 + quad * 4 + r,
                          __float_as_uint(m));
        }
}

// ---------------- pass 2: S'_i = sum_j exp(-a_i * d_ij) ----------------
__global__ __launch_bounds__(256, 4) void k_rowsum(float* ws) {
    __shared__ __align__(16) char lds[32768];
    const char* Ivb = (const char*)(ws + OFF_IV);
    const char* Tvb = (const char*)(ws + OFF_TV);
    const int tid = threadIdx.x, lane = tid & 63, wave = tid >> 6;
    const int wm = wave >> 1, quad = (lane >> 4) & 3, l15 = lane & 15;
    const int i0 = blockIdx.x * 128;
    const char* Ab = Ivb + (size_t)i0 * 512;
    float c1[4][4], run[4][4];
#pragma unroll
    for (int mt = 0; mt < 4; ++mt)
#pragma unroll
        for (int r = 0; r < 4; ++r) {
            int i = i0 + wm * 64 + mt * 16 + quad * 4 + r;
            float mm = __uint_as_float(((unsigned*)(ws + OFF_MROW))[i]);
            c1[mt][r] = -1.4426950408889634f * 2.0f / (mm + 1e-5f);  // -a*log2e
            run[mt][r] = 0.f;
        }
    for (int t = 0; t < 4; ++t) {
        int j0 = (blockIdx.y * 4 + t) * 128;
        v4f acc[4][4];
#pragma unroll
        for (int mt = 0; mt < 4; ++mt)
#pragma unroll
            for (int nt = 0; nt < 4; ++nt)
#pragma unroll
                for (int r = 0; r < 4; ++r) acc[mt][nt][r] = 0.f;
        tile_mma(Ab, Tvb + (size_t)j0 * 512, lds, tid, acc);
#pragma unroll
        for (int mt = 0; mt < 4; ++mt)
#pragma unroll
            for (int nt = 0; nt < 4; ++nt)
#pragma unroll
                for (int r = 0; r < 4; ++r) {
                    float d = fmaxf(0.5f - 0.5f * acc[mt][nt][r], 0.0f);
                    run[mt][r] += __builtin_amdgcn_exp2f(c1[mt][r] * d);
                }
    }
#pragma unroll
    for (int mt = 0; mt < 4; ++mt)
#pragma unroll
        for (int r = 0; r < 4; ++r) {
            float s = run[mt][r];
            for (int off = 1; off < 16; off <<= 1)
                s += __shfl_xor(s, off, 64);
            if (l15 == 0)
                atomicAdd(ws + OFF_WROW + i0 + wm * 64 + mt * 16 + quad * 4 + r, s);
        }
}

// ------- pass 3: vcol_j = min_i [ a_i * d_ij + ln S'_i ] -------------
// Tile rows = j (A from Tv), tile cols = i (B from Iv).
__global__ __launch_bounds__(256, 4) void k_colmin(float* ws) {
    __shared__ __align__(16) char lds[32768];
    const char* Ivb = (const char*)(ws + OFF_IV);
    const char* Tvb = (const char*)(ws + OFF_TV);
    const int tid = threadIdx.x, lane = tid & 63, wave = tid >> 6;
    const int wm = wave >> 1, wn = wave & 1, quad = (lane >> 4) & 3, l15 = lane & 15;
    const int j0 = blockIdx.x * 128;
    const char* Ab = Tvb + (size_t)j0 * 512;
    float vmin[4][4];
#pragma unroll
    for (int mt = 0; mt < 4; ++mt)
#pragma unroll
        for (int r = 0; r < 4; ++r) vmin[mt][r] = INFINITY;
    for (int t = 0; t < 4; ++t) {
        int ib = (blockIdx.y * 4 + t) * 128;
        v4f acc[4][4];
#pragma unroll
        for (int mt = 0; mt < 4; ++mt)
#pragma unroll
            for (int nt = 0; nt < 4; ++nt)
#pragma unroll
                for (int r = 0; r < 4; ++r) acc[mt][nt][r] = 0.f;
        tile_mma(Ab, Ivb + (size_t)ib * 512, lds, tid, acc);  // acc = cos[j][i]
#pragma unroll
        for (int nt = 0; nt < 4; ++nt) {
            int i = ib + wn * 64 + nt * 16 + l15;
            float mm = __uint_as_float(((unsigned*)(ws + OFF_MROW))[i]);
            float a = 2.0f / (mm + 1e-5f);
            float lw = __builtin_amdgcn_logf(ws[OFF_WROW + i]) * 0.6931471805599453f;
#pragma unroll
            for (int mt = 0; mt < 4; ++mt)
#pragma unroll
                for (int r = 0; r < 4; ++r) {
                    float d = fmaxf(0.5f - 0.5f * acc[mt][nt][r], 0.0f);
                    vmin[mt][r] = fminf(vmin[mt][r], a * d + lw);
                }
        }
    }
#pragma unroll
    for (int mt = 0; mt < 4; ++mt)
#pragma unroll
        for (int r = 0; r < 4; ++r) {
            float v = vmin[mt][r];
            for (int off = 1; off < 16; off <<= 1)
                v = fminf(v, __shfl_xor(v, off, 64));
            if (l15 == 0)
                atomicMin((unsigned*)(ws + OFF_VCOL) + j0 + wm * 64 + mt * 16 + quad * 4 + r,
                          __float_as_uint(v));
        }
}

// ---------------- final: parallel sum then scalar write ----------------
__global__ void k_fsum(float* ws) {
    __shared__ float red[256];
    int j0 = blockIdx.x * 256 + threadIdx.x;
    float s = expf(-__uint_as_float(((const unsigned*)(ws + OFF_VCOL))[j0]));
    red[threadIdx.x] = s;
    __syncthreads();
    for (int off = 128; off > 0; off >>= 1) {
        if (threadIdx.x < off) red[threadIdx.x] += red[threadIdx.x + off];
        __syncthreads();
    }
    if (threadIdx.x == 0) atomicAdd(ws + OFF_SUM, red[0]);
}

__global__ void k_fwrite(const float* __restrict__ ws, float* __restrict__ out) {
    out[0] = logf((float)Sn) - logf(ws[OFF_SUM]);
}

extern "C" void kernel_launch(void* const* d_in, const int* in_sizes, int n_in,
                              void* d_out, int out_size, void* d_ws, size_t ws_size,
                              hipStream_t stream) {
    const float* I = (const float*)d_in[0];
    const float* T = (const float*)d_in[1];
    float* ws = (float*)d_ws;
    float* out = (float*)d_out;

    k_init<<<36, 256, 0, stream>>>(ws);
    k_mean<<<Cn, 256, 0, stream>>>(T, ws);
    k_norm<<<144, 256, 0, stream>>>(I, T, ws);
    k_rowmin<<<dim3(72, 18), 256, 0, stream>>>(ws);
    k_rowsum<<<dim3(72, 18), 256, 0, stream>>>(ws);
    k_colmin<<<dim3(72, 18), 256, 0, stream>>>(ws);
    k_fsum<<<36, 256, 0, stream>>>(ws);
    k_fwrite<<<1, 1, 0, stream>>>(ws, out);
}

// Round 10
// 259.893 us; speedup vs baseline: 1.8142x; 1.8142x over previous
//
#include <hip/hip_runtime.h>
#include <math.h>

// Contextual loss, N=1, C=256, H=W=96 -> S=9216.
// loss = log(S) - log( sum_j exp( -vcol_j ) )
//   vcol_j = min_i [ a_i * d_ij + ln S'_i ]
//   S'_i   = sum_j exp( -a_i * d_ij )
//   a_i    = 2 / (m_i + 1e-5),  m_i = min_j d_ij,  d = clip((1-cos)/2, 0)
// cos = Iv^T Tv; Iv,Tv bf16, stored transposed [S][C] (K-contiguous, NT GEMM).
// R10: single GEMM pass (r8-proven 82 µs structure: direct-global A frags,
// 16 KB B slices via global_load_lds) that materializes d as fp16 in MFMA
// FRAGMENT LAYOUT (lane-coalesced 16 B pieces -- fixes r5's RMW-inflated
// scattered stores) + rowmin epilogue. Passes 2/3 are pure BW streams over
// the 166 MB D (L3-resident). Fallback to r8 3-GEMM path if ws too small.

typedef short v8s __attribute__((ext_vector_type(8)));
typedef float v4f __attribute__((ext_vector_type(4)));
typedef _Float16 v8h __attribute__((ext_vector_type(8)));

static constexpr int Sn = 9216;
static constexpr int Cn = 256;

// ws float offsets
static constexpr size_t OFF_MEAN = 0;                      // 256 floats
static constexpr size_t OFF_MROW = 256;                    // Sn uint bits (row min d)
static constexpr size_t OFF_WROW = 256 + 9216;             // Sn floats (S'_i)
static constexpr size_t OFF_VCOL = 256 + 2 * 9216;         // Sn uint bits (col min v)
static constexpr size_t OFF_SUM  = 256 + 3 * 9216;         // 1 float
static constexpr size_t OFF_ALW  = 256 + 4 * 9216;         // Sn float2 {a, lnS'}
static constexpr size_t OFF_IV   = 65536;                  // Sn*Cn bf16
static constexpr size_t OFF_TV   = 65536 + (size_t)Sn * Cn / 2;
// fp16 D in fragment layout: tile chunk (bi,jt,wave) = 8 KB;
// piece p (0..7) at chunkbase + p*1024 + lane*16.
static constexpr size_t OFF_D_B  = (size_t)16 << 20;
static constexpr size_t D_BYTES  = (size_t)72 * 72 * 4 * 8192;  // 166 MB
static constexpr size_t NEED_B   = OFF_D_B + D_BYTES;

__device__ __forceinline__ unsigned bf16rne(float x) {
    unsigned u = __float_as_uint(x);
    return (u + 0x7FFFu + ((u >> 16) & 1u)) >> 16;
}

__device__ __forceinline__ void gload_lds16(const void* g, void* l) {
    __builtin_amdgcn_global_load_lds(
        (const __attribute__((address_space(1))) unsigned*)g,
        (__attribute__((address_space(3))) unsigned*)l, 16, 0, 0);
}

// ---------------- init ----------------
__global__ void k_init(float* ws) {
    int t = blockIdx.x * 256 + threadIdx.x;
    if (t < Sn) {
        ((unsigned*)(ws + OFF_MROW))[t] = 0x7F800000u;  // +inf
        ws[OFF_WROW + t] = 0.0f;
        ((unsigned*)(ws + OFF_VCOL))[t] = 0x7F800000u;  // +inf
    }
    if (t == 0) ws[OFF_SUM] = 0.0f;
}

// ---------------- per-channel mean of T ----------------
__global__ void k_mean(const float* __restrict__ T, float* ws) {
    __shared__ float red[256];
    int c = blockIdx.x;
    float s = 0.f;
    for (int i = threadIdx.x; i < Sn; i += 256) s += T[(size_t)c * Sn + i];
    red[threadIdx.x] = s;
    __syncthreads();
    for (int off = 128; off > 0; off >>= 1) {
        if (threadIdx.x < off) red[threadIdx.x] += red[threadIdx.x + off];
        __syncthreads();
    }
    if (threadIdx.x == 0) ws[OFF_MEAN + c] = red[0] * (1.0f / Sn);
}

// ------- center + L2 normalize along C, emit bf16 transposed [S][C] -------
__global__ __launch_bounds__(256) void k_norm(const float* __restrict__ I,
                                              const float* __restrict__ T,
                                              float* ws) {
    __shared__ float mc[256];
    __shared__ float redI[4][64], redT[4][64];
    __shared__ float riS[64], rtS[64];
    const int tid = threadIdx.x, sl = tid & 63, cq = tid >> 6;
    const int s = blockIdx.x * 64 + sl;
    mc[tid] = ws[OFF_MEAN + tid];
    __syncthreads();
    float si = 0.f, st = 0.f;
    for (int c = cq * 64; c < cq * 64 + 64; ++c) {
        float xi = I[(size_t)c * Sn + s] - mc[c];
        float xt = T[(size_t)c * Sn + s] - mc[c];
        si += xi * xi;
        st += xt * xt;
    }
    redI[cq][sl] = si;
    redT[cq][sl] = st;
    __syncthreads();
    if (tid < 64) {
        float a = redI[0][tid] + redI[1][tid] + redI[2][tid] + redI[3][tid];
        float b = redT[0][tid] + redT[1][tid] + redT[2][tid] + redT[3][tid];
        riS[tid] = 1.0f / fmaxf(sqrtf(a), 1e-12f);
        rtS[tid] = 1.0f / fmaxf(sqrtf(b), 1e-12f);
    }
    __syncthreads();
    const float ri = riS[sl], rt = rtS[sl];
    unsigned short* Iv = (unsigned short*)(ws + OFF_IV);
    unsigned short* Tv = (unsigned short*)(ws + OFF_TV);
    uint4* Ivq = (uint4*)(Iv + (size_t)s * Cn);
    uint4* Tvq = (uint4*)(Tv + (size_t)s * Cn);
    for (int c8 = cq * 8; c8 < cq * 8 + 8; ++c8) {
        unsigned iw[4], tw[4];
#pragma unroll
        for (int h = 0; h < 4; ++h) {
            int c0 = c8 * 8 + 2 * h, c1 = c0 + 1;
            float i0 = (I[(size_t)c0 * Sn + s] - mc[c0]) * ri;
            float i1 = (I[(size_t)c1 * Sn + s] - mc[c1]) * ri;
            float t0 = (T[(size_t)c0 * Sn + s] - mc[c0]) * rt;
            float t1 = (T[(size_t)c1 * Sn + s] - mc[c1]) * rt;
            iw[h] = bf16rne(i0) | (bf16rne(i1) << 16);
            tw[h] = bf16rne(t0) | (bf16rne(t1) << 16);
        }
        Ivq[c8] = make_uint4(iw[0], iw[1], iw[2], iw[3]);
        Tvq[c8] = make_uint4(tw[0], tw[1], tw[2], tw[3]);
    }
}

// ---- r3/r8-proven staging: 16 KB K-slices, 8-chunk XOR swizzle ----
__device__ __forceinline__ void stage_slice(const char* Gb, char* lds,
                                            int kcs, int tid) {
    const int lane = tid & 63, wave = tid >> 6;
#pragma unroll
    for (int w = 0; w < 4; ++w) {
        int gi = wave * 4 + w;
        int row = gi * 8 + (lane >> 3);
        int p = lane & 7;
        int c = p ^ (row & 7);
        const char* g = Gb + (size_t)row * 512 + kcs * 128 + c * 16;
        gload_lds16(g, lds + gi * 1024);
    }
}

// A fragments straight from global (L2): 32 independent 16 B loads.
__device__ __forceinline__ void load_A(const v8s* __restrict__ Aq, int row0,
                                       int quad, int l15, v8s fa[4][8]) {
#pragma unroll
    for (int mt = 0; mt < 4; ++mt) {
        size_t row = row0 + mt * 16 + l15;
#pragma unroll
        for (int kk = 0; kk < 8; ++kk)
            fa[mt][kk] = Aq[row * 32 + kk * 4 + quad];
    }
}

__device__ __forceinline__ void tile_mma(const char* Bb, char* lds, int tid,
                                         const v8s fa[4][8], v4f acc[4][4]) {
    const int lane = tid & 63, wave = tid >> 6;
    const int wn = wave & 1, quad = (lane >> 4) & 3, l15 = lane & 15;
#pragma unroll
    for (int kc = 0; kc < 4; ++kc) {
        __syncthreads();
        stage_slice(Bb, lds, kc, tid);
        __syncthreads();
#pragma unroll
        for (int ks = 0; ks < 2; ++ks) {
            int c = ks * 4 + quad;
#pragma unroll
            for (int nt = 0; nt < 4; ++nt) {
                int row = wn * 64 + nt * 16 + l15;
                int p = c ^ (row & 7);
                v8s fb = *(const v8s*)(lds + row * 128 + p * 16);
#pragma unroll
                for (int mt = 0; mt < 4; ++mt)
                    acc[mt][nt] = __builtin_amdgcn_mfma_f32_16x16x32_bf16(
                        fa[mt][kc * 2 + ks], fb, acc[mt][nt], 0, 0, 0);
            }
        }
    }
}

// ======== BIG-WS pass 1: GEMM once, store fp16 D fragments + rowmin ========
__global__ __launch_bounds__(256, 2) void k_gemm_d(float* ws) {
    __shared__ __align__(16) char Bsb[16384];
    const v8s* Ivq = (const v8s*)(ws + OFF_IV);
    const char* Tvb = (const char*)(ws + OFF_TV);
    char* Dp = (char*)ws + OFF_D_B;
    const int tid = threadIdx.x, lane = tid & 63, wave = tid >> 6;
    const int wm = wave >> 1, quad = (lane >> 4) & 3, l15 = lane & 15;
    const int bi = blockIdx.x, i0 = bi * 128;
    v8s fa[4][8];
    load_A(Ivq, i0 + wm * 64, quad, l15, fa);
    float mv[4][4];
#pragma unroll
    for (int mt = 0; mt < 4; ++mt)
#pragma unroll
        for (int r = 0; r < 4; ++r) mv[mt][r] = INFINITY;
    for (int t = 0; t < 9; ++t) {
        int jt = blockIdx.y * 9 + t;
        v4f acc[4][4];
#pragma unroll
        for (int mt = 0; mt < 4; ++mt)
#pragma unroll
            for (int nt = 0; nt < 4; ++nt)
#pragma unroll
                for (int r = 0; r < 4; ++r) acc[mt][nt][r] = 0.f;
        tile_mma(Tvb + (size_t)jt * 128 * 512, Bsb, tid, fa, acc);
        char* cb = Dp + (((size_t)bi * 72 + jt) * 4 + wave) * 8192;
#pragma unroll
        for (int mt = 0; mt < 4; ++mt) {
#pragma unroll
            for (int cp = 0; cp < 2; ++cp) {
                v8h out;
#pragma unroll
                for (int k = 0; k < 4; ++k) {
                    float d0 = fmaxf(0.5f - 0.5f * acc[mt][2 * cp][k], 0.0f);
                    float d1 = fmaxf(0.5f - 0.5f * acc[mt][2 * cp + 1][k], 0.0f);
                    out[k] = (_Float16)d0;
                    out[4 + k] = (_Float16)d1;
                    mv[mt][k] = fminf(mv[mt][k], fminf(d0, d1));
                }
                *(v8h*)(cb + (mt * 2 + cp) * 1024 + lane * 16) = out;
            }
        }
    }
#pragma unroll
    for (int mt = 0; mt < 4; ++mt)
#pragma unroll
        for (int r = 0; r < 4; ++r) {
            float m = mv[mt][r];
            for (int off = 1; off < 16; off <<= 1)
                m = fminf(m, __shfl_xor(m, off, 64));
            if (l15 == 0)
                atomicMin((unsigned*)(ws + OFF_MROW) + i0 + wm * 64 + mt * 16 + quad * 4 + r,
                          __float_as_uint(m));
        }
}

// ---- pass 2 (stream): S'_i = sum_j exp(-a_i d_ij) over D fragments ----
__global__ __launch_bounds__(256) void k_rowsum_d(float* ws) {
    const char* Dp = (const char*)ws + OFF_D_B;
    const int tid = threadIdx.x, lane = tid & 63, wave = tid >> 6;
    const int wm = wave >> 1, quad = (lane >> 4) & 3, l15 = lane & 15;
    const int bi = blockIdx.x;
    float c1[4][4], run[4][4];
#pragma unroll
    for (int mt = 0; mt < 4; ++mt)
#pragma unroll
        for (int r = 0; r < 4; ++r) {
            int i = bi * 128 + wm * 64 + mt * 16 + quad * 4 + r;
            float mm = __uint_as_float(((unsigned*)(ws + OFF_MROW))[i]);
            c1[mt][r] = -1.4426950408889634f * 2.0f / (mm + 1e-5f);  // -a*log2e
            run[mt][r] = 0.f;
        }
    for (int t = 0; t < 9; ++t) {
        int jt = blockIdx.y * 9 + t;
        const char* cb = Dp + (((size_t)bi * 72 + jt) * 4 + wave) * 8192;
#pragma unroll
        for (int p = 0; p < 8; ++p) {
            v8h h = *(const v8h*)(cb + p * 1024 + lane * 16);
            int mt = p >> 1;
#pragma unroll
            for (int k = 0; k < 4; ++k) {
                run[mt][k] += __builtin_amdgcn_exp2f(c1[mt][k] * (float)h[k]);
                run[mt][k] += __builtin_amdgcn_exp2f(c1[mt][k] * (float)h[4 + k]);
            }
        }
    }
#pragma unroll
    for (int mt = 0; mt < 4; ++mt)
#pragma unroll
        for (int r = 0; r < 4; ++r) {
            float s = run[mt][r];
            for (int off = 1; off < 16; off <<= 1)
                s += __shfl_xor(s, off, 64);
            if (l15 == 0)
                atomicAdd(ws + OFF_WROW + bi * 128 + wm * 64 + mt * 16 + quad * 4 + r, s);
        }
}

// prep: {a_i, lnS'_i}
__global__ void k_prep(float* ws) {
    int i = blockIdx.x * 256 + threadIdx.x;
    float mm = __uint_as_float(((unsigned*)(ws + OFF_MROW))[i]);
    float a = 2.0f / (mm + 1e-5f);
    float lw = logf(ws[OFF_WROW + i]);
    ((float2*)(ws + OFF_ALW))[i] = make_float2(a, lw);
}

// ---- pass 3 (stream): vcol_j = min_i [a_i d_ij + lnS'_i] over D fragments ----
__global__ __launch_bounds__(256) void k_colmin_d(float* ws) {
    const char* Dp = (const char*)ws + OFF_D_B;
    const float2* alw = (const float2*)(ws + OFF_ALW);
    const int tid = threadIdx.x, lane = tid & 63, wave = tid >> 6;
    const int wm = wave >> 1, wn = wave & 1, quad = (lane >> 4) & 3, l15 = lane & 15;
    const int jt = blockIdx.x;
    float vmin[4];
#pragma unroll
    for (int nt = 0; nt < 4; ++nt) vmin[nt] = INFINITY;
    for (int t = 0; t < 9; ++t) {
        int bi = blockIdx.y * 9 + t;
        float av[4][4], lwv[4][4];
#pragma unroll
        for (int mt = 0; mt < 4; ++mt)
#pragma unroll
            for (int r = 0; r < 4; ++r) {
                float2 al = alw[bi * 128 + wm * 64 + mt * 16 + quad * 4 + r];
                av[mt][r] = al.x;
                lwv[mt][r] = al.y;
            }
        const char* cb = Dp + (((size_t)bi * 72 + jt) * 4 + wave) * 8192;
#pragma unroll
        for (int p = 0; p < 8; ++p) {
            v8h h = *(const v8h*)(cb + p * 1024 + lane * 16);
            int mt = p >> 1, nb = (p & 1) * 2;
#pragma unroll
            for (int k = 0; k < 4; ++k) {
                vmin[nb] = fminf(vmin[nb], av[mt][k] * (float)h[k] + lwv[mt][k]);
                vmin[nb + 1] = fminf(vmin[nb + 1],
                                     av[mt][k] * (float)h[4 + k] + lwv[mt][k]);
            }
        }
    }
    // reduce across quads (lane bits 4,5): cols shared by same l15
#pragma unroll
    for (int nt = 0; nt < 4; ++nt) {
        float v = vmin[nt];
        v = fminf(v, __shfl_xor(v, 16, 64));
        v = fminf(v, __shfl_xor(v, 32, 64));
        if (quad == 0) {
            v = fmaxf(v, 0.0f);  // keep positive-bit atomicMin valid
            atomicMin((unsigned*)(ws + OFF_VCOL) + jt * 128 + wn * 64 + nt * 16 + l15,
                      __float_as_uint(v));
        }
    }
}

// ======== FALLBACK (small ws): r8-proven 3-GEMM path ========
__global__ __launch_bounds__(256, 2) void k_rowmin(float* ws) {
    __shared__ __align__(16) char Bsb[16384];
    const v8s* Ivq = (const v8s*)(ws + OFF_IV);
    const char* Tvb = (const char*)(ws + OFF_TV);
    const int tid = threadIdx.x, lane = tid & 63, wave = tid >> 6;
    const int wm = wave >> 1, quad = (lane >> 4) & 3, l15 = lane & 15;
    const int i0 = blockIdx.x * 128;
    v8s fa[4][8];
    load_A(Ivq, i0 + wm * 64, quad, l15, fa);
    float mv[4][4];
#pragma unroll
    for (int mt = 0; mt < 4; ++mt)
#pragma unroll
        for (int r = 0; r < 4; ++r) mv[mt][r] = INFINITY;
    for (int t = 0; t < 4; ++t) {
        int j0 = (blockIdx.y * 4 + t) * 128;
        v4f acc[4][4];
#pragma unroll
        for (int mt = 0; mt < 4; ++mt)
#pragma unroll
            for (int nt = 0; nt < 4; ++nt)
#pragma unroll
                for (int r = 0; r < 4; ++r) acc[mt][nt][r] = 0.f;
        tile_mma(Tvb + (size_t)j0 * 512, Bsb, tid, fa, acc);
#pragma unroll
        for (int mt = 0; mt < 4; ++mt)
#pragma unroll
            for (int nt = 0; nt < 4; ++nt)
#pragma unroll
                for (int r = 0; r < 4; ++r) {
                    float d = fmaxf(0.5f - 0.5f * acc[mt][nt][r], 0.0f);
                    mv[mt][r] = fminf(mv[mt][r], d);
                }
    }
#pragma unroll
    for (int mt = 0; mt < 4; ++mt)
#pragma unroll
        for (int r = 0; r < 4; ++r) {
            float m = mv[mt][r];
            for (int off = 1; off < 16; off <<= 1)
                m = fminf(m, __shfl_xor(m, off, 64));
            if (l15 == 0)
                atomicMin((unsigned*)(ws + OFF_MROW) + i0 + wm * 64 + mt * 16 + quad * 4 + r,
                          __float_as_uint(m));
        }
}

__global__ __launch_bounds__(256, 2) void k_rowsum(float* ws) {
    __shared__ __align__(16) char Bsb[16384];
    const v8s* Ivq = (const v8s*)(ws + OFF_IV);
    const char* Tvb = (const char*)(ws + OFF_TV);
    const int tid = threadIdx.x, lane = tid & 63, wave = tid >> 6;
    const int wm = wave >> 1, quad = (lane >> 4) & 3, l15 = lane & 15;
    const int i0 = blockIdx.x * 128;
    v8s fa[4][8];
    load_A(Ivq, i0 + wm * 64, quad, l15, fa);
    float c1[4][4], run[4][4];
#pragma unroll
    for (int mt = 0; mt < 4; ++mt)
#pragma unroll
        for (int r = 0; r < 4; ++r) {
            int i = i0 + wm * 64 + mt * 16 + quad * 4 + r;
            float mm = __uint_as_float(((unsigned*)(ws + OFF_MROW))[i]);
            c1[mt][r] = -1.4426950408889634f * 2.0f / (mm + 1e-5f);
            run[mt][r] = 0.f;
        }
    for (int t = 0; t < 4; ++t) {
        int j0 = (blockIdx.y * 4 + t) * 128;
        v4f acc[4][4];
#pragma unroll
        for (int mt = 0; mt < 4; ++mt)
#pragma unroll
            for (int nt = 0; nt < 4; ++nt)
#pragma unroll
                for (int r = 0; r < 4; ++r) acc[mt][nt][r] = 0.f;
        tile_mma(Tvb + (size_t)j0 * 512, Bsb, tid, fa, acc);
#pragma unroll
        for (int mt = 0; mt < 4; ++mt)
#pragma unroll
            for (int nt = 0; nt < 4; ++nt)
#pragma unroll
                for (int r = 0; r < 4; ++r) {
                    float d = fmaxf(0.5f - 0.5f * acc[mt][nt][r], 0.0f);
                    run[mt][r] += __builtin_amdgcn_exp2f(c1[mt][r] * d);
                }
    }
#pragma unroll
    for (int mt = 0; mt < 4; ++mt)
#pragma unroll
        for (int r = 0; r < 4; ++r) {
            float s = run[mt][r];
            for (int off = 1; off < 16; off <<= 1)
                s += __shfl_xor(s, off, 64);
            if (l15 == 0)
                atomicAdd(ws + OFF_WROW + i0 + wm * 64 + mt * 16 + quad * 4 + r, s);
        }
}

__global__ __launch_bounds__(256, 2) void k_colmin(float* ws) {
    __shared__ __align__(16) char Bsb[16384];
    const char* Ivb = (const char*)(ws + OFF_IV);
    const v8s* Tvq = (const v8s*)(ws + OFF_TV);
    const int tid = threadIdx.x, lane = tid & 63, wave = tid >> 6;
    const int wm = wave >> 1, wn = wave & 1, quad = (lane >> 4) & 3, l15 = lane & 15;
    const int j0 = blockIdx.x * 128;
    v8s fa[4][8];
    load_A(Tvq, j0 + wm * 64, quad, l15, fa);
    float vmin[4][4];
#pragma unroll
    for (int mt = 0; mt < 4; ++mt)
#pragma unroll
        for (int r = 0; r < 4; ++r) vmin[mt][r] = INFINITY;
    for (int t = 0; t < 4; ++t) {
        int ib = (blockIdx.y * 4 + t) * 128;
        v4f acc[4][4];
#pragma unroll
        for (int mt = 0; mt < 4; ++mt)
#pragma unroll
            for (int nt = 0; nt < 4; ++nt)
#pragma unroll
                for (int r = 0; r < 4; ++r) acc[mt][nt][r] = 0.f;
        tile_mma(Ivb + (size_t)ib * 512, Bsb, tid, fa, acc);
#pragma unroll
        for (int nt = 0; nt < 4; ++nt) {
            int i = ib + wn * 64 + nt * 16 + l15;
            float mm = __uint_as_float(((unsigned*)(ws + OFF_MROW))[i]);
            float a = 2.0f / (mm + 1e-5f);
            float lw = __builtin_amdgcn_logf(ws[OFF_WROW + i]) * 0.6931471805599453f;
#pragma unroll
            for (int mt = 0; mt < 4; ++mt)
#pragma unroll
                for (int r = 0; r < 4; ++r) {
                    float d = fmaxf(0.5f - 0.5f * acc[mt][nt][r], 0.0f);
                    vmin[mt][r] = fminf(vmin[mt][r], a * d + lw);
                }
        }
    }
#pragma unroll
    for (int mt = 0; mt < 4; ++mt)
#pragma unroll
        for (int r = 0; r < 4; ++r) {
            float v = vmin[mt][r];
            for (int off = 1; off < 16; off <<= 1)
                v = fminf(v, __shfl_xor(v, off, 64));
            if (l15 == 0)
                atomicMin((unsigned*)(ws + OFF_VCOL) + j0 + wm * 64 + mt * 16 + quad * 4 + r,
                          __float_as_uint(v));
        }
}

// ---------------- final: parallel sum then scalar write ----------------
__global__ void k_fsum(float* ws) {
    __shared__ float red[256];
    int j0 = blockIdx.x * 256 + threadIdx.x;
    float s = expf(-__uint_as_float(((const unsigned*)(ws + OFF_VCOL))[j0]));
    red[threadIdx.x] = s;
    __syncthreads();
    for (int off = 128; off > 0; off >>= 1) {
        if (threadIdx.x < off) red[threadIdx.x] += red[threadIdx.x + off];
        __syncthreads();
    }
    if (threadIdx.x == 0) atomicAdd(ws + OFF_SUM, red[0]);
}

__global__ void k_fwrite(const float* __restrict__ ws, float* __restrict__ out) {
    out[0] = logf((float)Sn) - logf(ws[OFF_SUM]);
}

extern "C" void kernel_launch(void* const* d_in, const int* in_sizes, int n_in,
                              void* d_out, int out_size, void* d_ws, size_t ws_size,
                              hipStream_t stream) {
    const float* I = (const float*)d_in[0];
    const float* T = (const float*)d_in[1];
    float* ws = (float*)d_ws;
    float* out = (float*)d_out;

    k_init<<<36, 256, 0, stream>>>(ws);
    k_mean<<<Cn, 256, 0, stream>>>(T, ws);
    k_norm<<<144, 256, 0, stream>>>(I, T, ws);
    if (ws_size >= NEED_B) {
        k_gemm_d<<<dim3(72, 8), 256, 0, stream>>>(ws);
        k_rowsum_d<<<dim3(72, 8), 256, 0, stream>>>(ws);
        k_prep<<<36, 256, 0, stream>>>(ws);
        k_colmin_d<<<dim3(72, 8), 256, 0, stream>>>(ws);
    } else {
        k_rowmin<<<dim3(72, 18), 256, 0, stream>>>(ws);
        k_rowsum<<<dim3(72, 18), 256, 0, stream>>>(ws);
        k_colmin<<<dim3(72, 18), 256, 0, stream>>>(ws);
    }
    k_fsum<<<36, 256, 0, stream>>>(ws);
    k_fwrite<<<1, 1, 0, stream>>>(ws, out);
}